// Round 5
// baseline (413.190 us; speedup 1.0000x reference)
//
#include <hip/hip_runtime.h>
#include <hip/hip_bf16.h>

typedef float  f32x4  __attribute__((ext_vector_type(4)));
typedef __bf16 bf16x8 __attribute__((ext_vector_type(8)));
typedef short  s16x8  __attribute__((ext_vector_type(8)));
typedef short  s16x4  __attribute__((ext_vector_type(4)));

// fp32 -> bf16 round-to-nearest-even (raw bits in short)
__device__ __forceinline__ short f2b(float f) {
  unsigned u = __builtin_bit_cast(unsigned, f);
  u = (u + 0x7fffu + ((u >> 16) & 1u)) >> 16;
  return (short)u;
}
// bf16 bits -> fp32 (exact)
__device__ __forceinline__ float b2f(short s) {
  unsigned u = ((unsigned)(unsigned short)s) << 16;
  return __builtin_bit_cast(float, u);
}
// 4 fp32 -> 4 bf16 (packed cvt)
__device__ __forceinline__ s16x4 pack4(f32x4 a) {
  union { s16x4 v; __hip_bfloat162 h[2]; } u;
  u.h[0] = __float22bfloat162_rn(make_float2(a[0], a[1]));
  u.h[1] = __float22bfloat162_rn(make_float2(a[2], a[3]));
  return u.v;
}

// W [2][256 c][256 d] fp32  ->  Wt [2][256 d][256 c] bf16 (B-operand friendly)
__global__ void prep_wt(const float* __restrict__ W, short* __restrict__ Wt) {
  int q = blockIdx.x * blockDim.x + threadIdx.x;   // 0..32767, each handles 4 elems
  int mat = q >> 14;
  int rem = q & 16383;
  int d   = rem >> 6;
  int c4  = (rem & 63) << 2;
  const float* src = W + mat * 65536;
  s16x4 o;
  #pragma unroll
  for (int i = 0; i < 4; ++i) o[i] = f2b(src[(c4 + i) * 256 + d]);
  *(s16x4*)&Wt[q << 2] = o;   // flat = mat*65536 + d*256 + c4
}

// R9 = R8 with the batch tile halved: 34 rows (2 graph-groups) per block.
//  R8 measured: spill gone (WRITE=139MB=true output), but OccupancyPercent 11%
//  at VGPR=188 -> floor(512/188)=2 waves/SIMD = 2 blocks/CU; the serial
//  stage->K-loop->epilogue chain has nothing to overlap with -> latency-bound
//  (all pipes <21%). The VGPR consumers are acc[5][4]=80 and the 17-deep
//  staging burst. Halving the tile cuts acc to [3][4]=48 and staging to 9
//  in-flight loads, targeting VGPR ~130-160 -> 3 waves/SIMD = 12 waves/CU
//  (+50% TLP), grid 8192 (better tail), per-block serial time halved.
//  MFMA padding waste (48 rows computed vs 34 used) is irrelevant at 7.6%
//  MfmaUtil. Epilogue identical in structure, reindexed for 2 groups/tile.
//  XCD-pair swizzle kept (8192 % 8 == 0, bijective).
__global__ __launch_bounds__(256)
void fused_mgc(const float* __restrict__ x, const short* __restrict__ Wt,
               const float* __restrict__ M, const float* __restrict__ adj,
               const float* __restrict__ adj2, const float* __restrict__ bias,
               float* __restrict__ out) {
  __shared__ short smem[8976];    // xs[34][264] | union | sbuf[34][132]+gbuf[34][132]
  __shared__ float aoff[289];     // symmetrized A, diagonal zeroed
  __shared__ float diagl[17];     // diag of A

  const int tid  = threadIdx.x;
  const int lane = tid & 63;
  const int wv   = tid >> 6;
  const int m16  = lane & 15;
  const int qd   = lane >> 4;

  // XCD-pair swizzle: consecutive blockIdx round-robin across 8 XCDs, so
  // phys&7 = XCD. Pair consecutive iseq into one (bt, ct=0/1) tile on the
  // SAME XCD -> x tile HBM-fetched once, partner hits that XCD's L2.
  const int phys = blockIdx.x;
  const int xcd  = phys & 7;
  const int iseq = phys >> 3;                // 0..1023 within this XCD
  const int bt   = xcd * 512 + (iseq >> 1);  // batch tile: rows bt*34 .. +34
  const int ct   = iseq & 1;                 // col tile (128 d); pair shares x

  for (int idx = tid; idx < 289; idx += 256) {
    int i = idx / 17, j = idx - i * 17;
    float v = 0.5f * ((adj[i*17+j] + adj2[i*17+j]) + (adj[j*17+i] + adj2[j*17+i]));
    aoff[idx] = (i == j) ? 0.0f : v;
    if (i == j) diagl[i] = adj[i*17+i] + adj2[i*17+i];
  }

  // ---- stage x tile: 34 rows x 256 k, fp32 -> bf16 LDS (stride 264 shorts) ----
  {
    const float* xbase = x + (size_t)bt * 34 * 256;
    const int c4 = (tid & 63) << 2;   // col quad: 64 quads = 256 cols = 1 row/wave-op
    const int r0 = tid >> 6;          // 0..3
    #pragma unroll
    for (int it = 0; it < 9; ++it) {
      int row = r0 + it * 4;
      if (row < 34) {
        f32x4 v = *(const f32x4*)&xbase[row * 256 + c4];
        *(s16x4*)&smem[row * 264 + c4] = pack4(v);
      }
    }
  }

  f32x4 acc[3][4];  // [rowfrag][mat*2+colfrag]
  #pragma unroll
  for (int a = 0; a < 3; ++a)
    #pragma unroll
    for (int b = 0; b < 4; ++b) acc[a][b] = (f32x4)0.0f;

  const short* wbase = Wt + (ct * 128 + wv * 32 + m16) * 256;  // + mat*65536 + cf*4096

  __syncthreads();   // xs ready

  // A-row indices (clamped: rows 34..47 read row 33; their C-rows are never stored)
  int arow[3];
  #pragma unroll
  for (int rf = 0; rf < 3; ++rf) {
    int r = rf * 16 + m16;
    arow[rf] = (r < 34 ? r : 33) * 264;
  }

  #pragma unroll
  for (int ks = 0; ks < 8; ++ks) {
    const int kq = ks * 32 + qd * 8;
    bf16x8 bfr[4];
    #pragma unroll
    for (int mc = 0; mc < 4; ++mc) {
      int mat = mc >> 1, cf = mc & 1;
      s16x8 t = *(const s16x8*)&wbase[mat * 65536 + cf * 4096 + kq];
      bfr[mc] = __builtin_bit_cast(bf16x8, t);
    }
    #pragma unroll
    for (int rf = 0; rf < 3; ++rf) {
      s16x8 t = *(const s16x8*)&smem[arow[rf] + kq];
      bf16x8 af = __builtin_bit_cast(bf16x8, t);
      #pragma unroll
      for (int mc = 0; mc < 4; ++mc)
        acc[rf][mc] = __builtin_amdgcn_mfma_f32_16x16x32_bf16(af, bfr[mc], acc[rf][mc], 0, 0, 0);
    }
  }

  __syncthreads();   // all waves done reading xs; reuse smem for epilogue
  short* sbuf = smem;          // [34][132] bf16: diag_i*M*h0
  short* gbuf = smem + 4488;   // [34][132] bf16: M*h1

  // phase 1: registers (C-layout: col=lane&15, row=(lane>>4)*4+reg) -> LDS as bf16
  #pragma unroll
  for (int rf = 0; rf < 3; ++rf) {
    #pragma unroll
    for (int cf = 0; cf < 2; ++cf) {
      int c = wv * 32 + cf * 16 + m16;
      #pragma unroll
      for (int reg = 0; reg < 4; ++reg) {
        int r = rf * 16 + qd * 4 + reg;
        if (r < 34) {
          int n = r % 17;
          float mv = M[n * 256 + ct * 128 + c];
          sbuf[r * 132 + c] = f2b(diagl[n] * mv * acc[rf][cf][reg]);
          gbuf[r * 132 + c] = f2b(mv * acc[rf][2 + cf][reg]);
        }
      }
    }
  }
  __syncthreads();
  // phase 2: mixing. i,j uniform across threads -> aoff reads are broadcasts.
  const int d7   = tid & 127;
  const int g    = tid >> 7;       // batch-group within tile (0..1)
  const float bi = bias[ct * 128 + d7];
  {
    int rbase = g * 17;
    float gr[17];
    #pragma unroll
    for (int j = 0; j < 17; ++j) gr[j] = b2f(gbuf[(rbase + j) * 132 + d7]);
    #pragma unroll
    for (int i = 0; i < 17; ++i) {
      float s = b2f(sbuf[(rbase + i) * 132 + d7]) + bi;
      #pragma unroll
      for (int j = 0; j < 17; ++j) s += aoff[i * 17 + j] * gr[j];
      out[((bt * 2 + g) * 17 + i) * 256 + ct * 128 + d7] = s;
    }
  }
}

extern "C" void kernel_launch(void* const* d_in, const int* in_sizes, int n_in,
                              void* d_out, int out_size, void* d_ws, size_t ws_size,
                              hipStream_t stream) {
  const float* x    = (const float*)d_in[0];
  const float* W    = (const float*)d_in[1];
  const float* M    = (const float*)d_in[2];
  const float* adj  = (const float*)d_in[3];
  const float* adj2 = (const float*)d_in[4];
  const float* bias = (const float*)d_in[5];
  float* out = (float*)d_out;
  short* Wt  = (short*)d_ws;   // 262144 B scratch for transposed bf16 weights

  prep_wt<<<128, 256, 0, stream>>>(W, Wt);
  fused_mgc<<<8192, 256, 0, stream>>>(x, Wt, M, adj, adj2, bias, out);
}

// Round 6
// 366.307 us; speedup vs baseline: 1.1280x; 1.1280x over previous
//
#include <hip/hip_runtime.h>
#include <hip/hip_bf16.h>

typedef float  f32x4  __attribute__((ext_vector_type(4)));
typedef __bf16 bf16x8 __attribute__((ext_vector_type(8)));
typedef short  s16x8  __attribute__((ext_vector_type(8)));
typedef short  s16x4  __attribute__((ext_vector_type(4)));

// fp32 -> bf16 round-to-nearest-even (raw bits in short)
__device__ __forceinline__ short f2b(float f) {
  unsigned u = __builtin_bit_cast(unsigned, f);
  u = (u + 0x7fffu + ((u >> 16) & 1u)) >> 16;
  return (short)u;
}
// bf16 bits -> fp32 (exact)
__device__ __forceinline__ float b2f(short s) {
  unsigned u = ((unsigned)(unsigned short)s) << 16;
  return __builtin_bit_cast(float, u);
}
// 4 fp32 -> 4 bf16 (packed cvt)
__device__ __forceinline__ s16x4 pack4(f32x4 a) {
  union { s16x4 v; __hip_bfloat162 h[2]; } u;
  u.h[0] = __float22bfloat162_rn(make_float2(a[0], a[1]));
  u.h[1] = __float22bfloat162_rn(make_float2(a[2], a[3]));
  return u.v;
}

// W [2][256 c][256 d] fp32  ->  Wt [2][256 d][256 c] bf16 (B-operand friendly)
__global__ void prep_wt(const float* __restrict__ W, short* __restrict__ Wt) {
  int q = blockIdx.x * blockDim.x + threadIdx.x;   // 0..32767, each handles 4 elems
  int mat = q >> 14;
  int rem = q & 16383;
  int d   = rem >> 6;
  int c4  = (rem & 63) << 2;
  const float* src = W + mat * 65536;
  s16x4 o;
  #pragma unroll
  for (int i = 0; i < 4; ++i) o[i] = f2b(src[(c4 + i) * 256 + d]);
  *(s16x4*)&Wt[q << 2] = o;   // flat = mat*65536 + d*256 + c4
}

// R10: persistent blocks + register-prefetch pipeline.
//  R8 (224us, 2 blk/CU) vs R9 (244us, ~8 blk/CU) measured: TLP is NOT the
//  lever -- every pipe <21%, the cost is per-block exposed global latency
//  (x staging + W L2 loads + aoff recompute) serialized by barriers, repaid
//  8192x. Aggregate floors: MFMA ~20us, VALU ~15us, HBM ~45-50us.
//  Fix = pipeline, not occupancy:
//   - grid 1024 persistent blocks, each does 8 consecutive 34-row tiles at a
//     FIXED ct: preamble paid once per 8 items; W/M/bias slices stay L2-hot.
//   - T14 async-stage: next tile's 9 f32x4 x-loads issued into REGISTERS
//     right after the post-pack barrier, consumed one iteration later.
//     HBM latency (~0.4us) hides under K-loop+epilogue (~2us).
//   - M slice staged to LDS once per block (8.7KB): phase1 reads LDS, not L2.
//   - LDS overlay: sbuf/gbuf reuse the xs region (exactly 8976 shorts each
//     side); barrier at loop end protects phase2 readers from next pack.
//     27.9KB/block -> LDS allows 5 blocks/CU; VGPR will decide (~3-4).
//  Barriers per iter: b1 post-pack (xs ready, phase2(t-1) done),
//  b2 post-K (xs free for phase1 overlay writes; drains t+1 prefetch, covered),
//  b3 post-phase1 (sbuf/gbuf ready), b4 post-phase2 (overlay safe for pack).
__global__ __launch_bounds__(256)
void fused_mgc(const float* __restrict__ x, const short* __restrict__ Wt,
               const float* __restrict__ M, const float* __restrict__ adj,
               const float* __restrict__ adj2, const float* __restrict__ bias,
               float* __restrict__ out) {
  __shared__ short xs[8976];    // [34][264] bf16 | overlay | sbuf[34][132]+gbuf[34][132]
  __shared__ float ms[2176];    // [17][128] fp32: M slice for this ct
  __shared__ float aoff[289];   // symmetrized A, diagonal zeroed
  __shared__ float diagl[17];   // diag of A

  const int tid  = threadIdx.x;
  const int lane = tid & 63;
  const int wv   = tid >> 6;
  const int m16  = lane & 15;
  const int qd   = lane >> 4;

  // XCD mapping: phys&7 = XCD. ct0/ct1 partners of the same bt-range land on
  // the same XCD consecutively -> x tiles shared via that XCD's L2.
  const int phys   = blockIdx.x;           // 0..1023
  const int xcd    = phys & 7;
  const int iseq   = phys >> 3;            // 0..127 within this XCD
  const int ct     = iseq & 1;             // col tile (128 d), fixed per block
  const int btbase = (xcd * 64 + (iseq >> 1)) * 8;   // 8 consecutive bt tiles

  const int c4 = (tid & 63) << 2;   // col quad for staging
  const int r0 = tid >> 6;          // 0..3

  // ---- prologue: issue item-0 x loads first (hide under preamble) ----
  f32x4 xp[9];
  {
    const float* xb = x + (size_t)btbase * 34 * 256;
    #pragma unroll
    for (int it = 0; it < 9; ++it) {
      int row = r0 + it * 4;
      if (row < 34) xp[it] = *(const f32x4*)&xb[row * 256 + c4];
    }
  }
  // aoff/diagl (once per block, amortized over 8 items)
  for (int idx = tid; idx < 289; idx += 256) {
    int i = idx / 17, j = idx - i * 17;
    float v = 0.5f * ((adj[i*17+j] + adj2[i*17+j]) + (adj[j*17+i] + adj2[j*17+i]));
    aoff[idx] = (i == j) ? 0.0f : v;
    if (i == j) diagl[i] = adj[i*17+i] + adj2[i*17+i];
  }
  // M slice -> LDS (17 x 128 fp32, coalesced f32x4)
  for (int q = tid; q < 544; q += 256) {
    int n = q >> 5, cq = (q & 31) << 2;
    *(f32x4*)&ms[n * 128 + cq] = *(const f32x4*)&M[n * 256 + ct * 128 + cq];
  }

  const short* wbase = Wt + (ct * 128 + wv * 32 + m16) * 256;  // + mat*65536 + cf*4096

  // A-row indices (clamped: rows 34..47 read row 33; their C-rows never stored)
  int arow[3];
  #pragma unroll
  for (int rf = 0; rf < 3; ++rf) {
    int r = rf * 16 + m16;
    arow[rf] = (r < 34 ? r : 33) * 264;
  }

  const int d7   = tid & 127;
  const int g    = tid >> 7;            // batch-group within tile (0..1)
  const float bi = bias[ct * 128 + d7];

  for (int t = 0; t < 8; ++t) {
    const int bt = btbase + t;

    // ---- pack prefetched regs -> xs (bf16, stride 264) ----
    #pragma unroll
    for (int it = 0; it < 9; ++it) {
      int row = r0 + it * 4;
      if (row < 34) *(s16x4*)&xs[row * 264 + c4] = pack4(xp[it]);
    }
    __syncthreads();   // b1: xs ready (iter0: ms/aoff too); phase2(t-1) done

    // ---- issue prefetch for item t+1 into registers ----
    if (t < 7) {
      const float* xb = x + (size_t)(bt + 1) * 34 * 256;
      #pragma unroll
      for (int it = 0; it < 9; ++it) {
        int row = r0 + it * 4;
        if (row < 34) xp[it] = *(const f32x4*)&xb[row * 256 + c4];
      }
    }

    // ---- K-loop ----
    f32x4 acc[3][4];  // [rowfrag][mat*2+colfrag]
    #pragma unroll
    for (int a = 0; a < 3; ++a)
      #pragma unroll
      for (int b = 0; b < 4; ++b) acc[a][b] = (f32x4)0.0f;

    #pragma unroll
    for (int ks = 0; ks < 8; ++ks) {
      const int kq = ks * 32 + qd * 8;
      bf16x8 bfr[4];
      #pragma unroll
      for (int mc = 0; mc < 4; ++mc) {
        int mat = mc >> 1, cf = mc & 1;
        s16x8 w = *(const s16x8*)&wbase[mat * 65536 + cf * 4096 + kq];
        bfr[mc] = __builtin_bit_cast(bf16x8, w);
      }
      #pragma unroll
      for (int rf = 0; rf < 3; ++rf) {
        s16x8 a8 = *(const s16x8*)&xs[arow[rf] + kq];
        bf16x8 af = __builtin_bit_cast(bf16x8, a8);
        #pragma unroll
        for (int mc = 0; mc < 4; ++mc)
          acc[rf][mc] = __builtin_amdgcn_mfma_f32_16x16x32_bf16(af, bfr[mc], acc[rf][mc], 0, 0, 0);
      }
    }
    __syncthreads();   // b2: xs readers done -> overlay writable; prefetch drained (covered by K)

    // ---- phase 1: acc -> sbuf/gbuf (overlaid on xs), M from LDS ----
    short* sbuf = xs;           // [34][132] bf16: diag_i*M*h0
    short* gbuf = xs + 4488;    // [34][132] bf16: M*h1
    #pragma unroll
    for (int rf = 0; rf < 3; ++rf) {
      #pragma unroll
      for (int cf = 0; cf < 2; ++cf) {
        int c = wv * 32 + cf * 16 + m16;
        #pragma unroll
        for (int reg = 0; reg < 4; ++reg) {
          int r = rf * 16 + qd * 4 + reg;
          if (r < 34) {
            int n = r - (r >= 17 ? 17 : 0);
            float mv = ms[n * 128 + c];
            sbuf[r * 132 + c] = f2b(diagl[n] * mv * acc[rf][cf][reg]);
            gbuf[r * 132 + c] = f2b(mv * acc[rf][2 + cf][reg]);
          }
        }
      }
    }
    __syncthreads();   // b3: sbuf/gbuf ready

    // ---- phase 2: mixing; aoff reads broadcast ----
    {
      int rbase = g * 17;
      float gr[17];
      #pragma unroll
      for (int j = 0; j < 17; ++j) gr[j] = b2f(gbuf[(rbase + j) * 132 + d7]);
      #pragma unroll
      for (int i = 0; i < 17; ++i) {
        float s = b2f(sbuf[(rbase + i) * 132 + d7]) + bi;
        #pragma unroll
        for (int j = 0; j < 17; ++j) s += aoff[i * 17 + j] * gr[j];
        out[((bt * 2 + g) * 17 + i) * 256 + ct * 128 + d7] = s;
      }
    }
    __syncthreads();   // b4: phase2 readers done before next pack overwrites overlay
  }
}

extern "C" void kernel_launch(void* const* d_in, const int* in_sizes, int n_in,
                              void* d_out, int out_size, void* d_ws, size_t ws_size,
                              hipStream_t stream) {
  const float* x    = (const float*)d_in[0];
  const float* W    = (const float*)d_in[1];
  const float* M    = (const float*)d_in[2];
  const float* adj  = (const float*)d_in[3];
  const float* adj2 = (const float*)d_in[4];
  const float* bias = (const float*)d_in[5];
  float* out = (float*)d_out;
  short* Wt  = (short*)d_ws;   // 262144 B scratch for transposed bf16 weights

  prep_wt<<<128, 256, 0, stream>>>(W, Wt);
  fused_mgc<<<1024, 256, 0, stream>>>(x, Wt, M, adj, adj2, bias, out);
}